// Round 1
// baseline (319.764 us; speedup 1.0000x reference)
//
#include <hip/hip_runtime.h>

// CrossNet fused kernel: out = initial * (X @ alphas) + X + bias
// B=16384 rows, D=2048 cols, fp32. One wave per row.
//
// R1: latency-bound fix. Previous build allocated only 32 VGPRs -> the
// compiler re-loaded X in the epilogue and each wave had ~8 loads in
// flight (2.4 TB/s, 38% of achievable). This version issues ALL row
// loads (X, initial) up front, folds bias pre-reduce, and pins the
// values in VGPRs (asm keep-alive) so the epilogue has zero memory
// latency on its critical path. amdgpu_waves_per_eu(4,8) raises the
// register budget to 128 so the allocator keeps 64+ live VGPRs.

#define CN_D 2048
#define CN_ROWS 16384

typedef float vfloat4 __attribute__((ext_vector_type(4)));

__global__ __attribute__((amdgpu_waves_per_eu(4, 8)))
__launch_bounds__(256) void crossnet_kernel(
    const float* __restrict__ initial,
    const float* __restrict__ X,
    const float* __restrict__ alphas,
    const float* __restrict__ bias,
    float* __restrict__ out)
{
    const int wave = threadIdx.x >> 6;          // 0..3
    const int lane = threadIdx.x & 63;
    const int row  = (blockIdx.x << 2) + wave;  // 4 rows per block

    const vfloat4* __restrict__ Xrow = (const vfloat4*)(X       + (size_t)row * CN_D);
    const vfloat4* __restrict__ Irow = (const vfloat4*)(initial + (size_t)row * CN_D);
    const vfloat4* __restrict__ A4   = (const vfloat4*)alphas;   // (D,1) contiguous
    const vfloat4* __restrict__ B4   = (const vfloat4*)bias;
    vfloat4*       __restrict__ Orow = (vfloat4*)(out + (size_t)row * CN_D);

    // D/4 = 512 float4 per row; 64 lanes x 8 chunks, coalesced.
    vfloat4 x[8];   // becomes t = X + bias before the reduce
    vfloat4 fi[8];  // initial, held across the reduce

    // Issue all 16 HBM row loads first: maximum memory-level parallelism.
#pragma unroll
    for (int k = 0; k < 8; ++k) x[k]  = Xrow[(k << 6) + lane];
#pragma unroll
    for (int k = 0; k < 8; ++k) fi[k] = Irow[(k << 6) + lane];

    // Dot product against alphas (alphas is 8 KB -> L2-resident).
    float acc = 0.0f;
#pragma unroll
    for (int k = 0; k < 8; ++k) {
        const vfloat4 a = A4[(k << 6) + lane];
        acc += x[k].x * a.x + x[k].y * a.y + x[k].z * a.z + x[k].w * a.w;
    }

    // Fold bias into X BEFORE the reduce (independent of scale), so the
    // post-reduce path is pure FMA + store.
#pragma unroll
    for (int k = 0; k < 8; ++k) {
        const vfloat4 b = B4[(k << 6) + lane];
        x[k] += b;
    }

    // Pin t and initial in VGPRs: the values are now opaque, so the
    // allocator cannot "save registers" by re-loading them after the
    // reduce (which is what capped the previous build at 8 loads in
    // flight per wave).
#pragma unroll
    for (int k = 0; k < 8; ++k) {
        asm volatile("" : "+v"(x[k]));
        asm volatile("" : "+v"(fi[k]));
    }

    // 64-lane butterfly; xor pattern leaves the full sum in every lane.
#pragma unroll
    for (int off = 32; off > 0; off >>= 1)
        acc += __shfl_xor(acc, off, 64);

    // Epilogue: zero loads on the critical path. Non-temporal stores so
    // the 134 MB output stream does not evict X/initial from L3.
#pragma unroll
    for (int k = 0; k < 8; ++k) {
        vfloat4 o;
        o.x = fmaf(fi[k].x, acc, x[k].x);
        o.y = fmaf(fi[k].y, acc, x[k].y);
        o.z = fmaf(fi[k].z, acc, x[k].z);
        o.w = fmaf(fi[k].w, acc, x[k].w);
        __builtin_nontemporal_store(o, &Orow[(k << 6) + lane]);
    }
}

extern "C" void kernel_launch(void* const* d_in, const int* in_sizes, int n_in,
                              void* d_out, int out_size, void* d_ws, size_t ws_size,
                              hipStream_t stream) {
    const float* initial = (const float*)d_in[0];
    const float* X       = (const float*)d_in[1];
    const float* alphas  = (const float*)d_in[2];
    const float* bias    = (const float*)d_in[3];
    float* out = (float*)d_out;

    // 16384 rows / 4 rows per block = 4096 blocks of 256 threads.
    crossnet_kernel<<<CN_ROWS / 4, 256, 0, stream>>>(initial, X, alphas, bias, out);
}

// Round 2
// 308.262 us; speedup vs baseline: 1.0373x; 1.0373x over previous
//
#include <hip/hip_runtime.h>

// CrossNet fused kernel: out = initial * (X @ alphas) + X + bias
// B=16384 rows, D=2048 cols, fp32. One wave per row.
//
// R2: single memory phase per row. Baseline had two serialized HBM
// waits (X-load ... reduce ... I-load), leaving only ~12 loads/wave in
// flight duty-weighted -> 2.4 TB/s. Here all 24 row loads (X, initial,
// alphas, bias) issue before the reduce, and a DATAFLOW fence (acc
// rewritten as a function of fi/x via non-volatile asm) makes it
// illegal to schedule the shuffle chain before the initial-loads
// complete -- so fi stays in VGPRs and the post-reduce path is pure
// FMA + store. R1's volatile keep-alive pins had no dataflow edge to
// the reduce and were sunk past it (VGPR stayed 44); its waves_per_eu
// and nontemporal-store knobs regressed occupancy/L3 and are reverted.

#define CN_D 2048
#define CN_ROWS 16384

typedef float vfloat4 __attribute__((ext_vector_type(4)));

__global__ __launch_bounds__(256) void crossnet_kernel(
    const float* __restrict__ initial,
    const float* __restrict__ X,
    const float* __restrict__ alphas,
    const float* __restrict__ bias,
    float* __restrict__ out)
{
    const int wave = threadIdx.x >> 6;          // 0..3
    const int lane = threadIdx.x & 63;
    const int row  = (blockIdx.x << 2) + wave;  // 4 rows per block

    const vfloat4* __restrict__ Xrow = (const vfloat4*)(X       + (size_t)row * CN_D);
    const vfloat4* __restrict__ Irow = (const vfloat4*)(initial + (size_t)row * CN_D);
    const vfloat4* __restrict__ A4   = (const vfloat4*)alphas;   // 8 KB, L2-resident
    const vfloat4* __restrict__ B4   = (const vfloat4*)bias;     // 8 KB, L2-resident
    vfloat4*       __restrict__ Orow = (vfloat4*)(out + (size_t)row * CN_D);

    // D/4 = 512 float4 per row; 64 lanes x 8 chunks, coalesced.
    vfloat4 x[8];   // becomes t = X + bias
    vfloat4 fi[8];  // initial, held across the reduce

    // Both HBM streams issued back-to-back: 16 dwordx4 in flight/wave.
#pragma unroll
    for (int k = 0; k < 8; ++k) x[k]  = Xrow[(k << 6) + lane];
#pragma unroll
    for (int k = 0; k < 8; ++k) fi[k] = Irow[(k << 6) + lane];

    // Dot against alphas (L2) while the HBM loads drain.
    float acc = 0.0f;
#pragma unroll
    for (int k = 0; k < 8; ++k) {
        const vfloat4 a = A4[(k << 6) + lane];
        acc = fmaf(x[k].x, a.x, acc);
        acc = fmaf(x[k].y, a.y, acc);
        acc = fmaf(x[k].z, a.z, acc);
        acc = fmaf(x[k].w, a.w, acc);
    }

    // Fold bias before the reduce: post-reduce path is pure FMA+store.
#pragma unroll
    for (int k = 0; k < 8; ++k)
        x[k] += B4[(k << 6) + lane];

    // DATAFLOW fence: acc (the reduce input) is declared to depend on
    // every fi/x value. The shuffle chain consumes the rewritten acc,
    // so the scheduler cannot hoist the reduce above these loads, and
    // fi/x remain live in VGPRs across it (no re-load phase). This is
    // a true dependence, unlike R1's volatile pins which plain FP code
    // was free to move across.
#pragma unroll
    for (int k = 0; k < 8; ++k)
        asm("" : "+v"(acc) : "v"(fi[k]), "v"(x[k]));

    // 64-lane butterfly; xor leaves the full sum in every lane.
#pragma unroll
    for (int off = 32; off > 0; off >>= 1)
        acc += __shfl_xor(acc, off, 64);

    // Epilogue: zero memory latency on the critical path.
#pragma unroll
    for (int k = 0; k < 8; ++k) {
        vfloat4 o;
        o.x = fmaf(fi[k].x, acc, x[k].x);
        o.y = fmaf(fi[k].y, acc, x[k].y);
        o.z = fmaf(fi[k].z, acc, x[k].z);
        o.w = fmaf(fi[k].w, acc, x[k].w);
        Orow[(k << 6) + lane] = o;
    }
}

extern "C" void kernel_launch(void* const* d_in, const int* in_sizes, int n_in,
                              void* d_out, int out_size, void* d_ws, size_t ws_size,
                              hipStream_t stream) {
    const float* initial = (const float*)d_in[0];
    const float* X       = (const float*)d_in[1];
    const float* alphas  = (const float*)d_in[2];
    const float* bias    = (const float*)d_in[3];
    float* out = (float*)d_out;

    // 16384 rows / 4 rows per block = 4096 blocks of 256 threads.
    crossnet_kernel<<<CN_ROWS / 4, 256, 0, stream>>>(initial, X, alphas, bias, out);
}